// Round 3
// baseline (207.480 us; speedup 1.0000x reference)
//
#include <hip/hip_runtime.h>
#include <hip/hip_bf16.h>

// Shapes (fixed for this problem)
#define S_LEN 1024
#define D_DIM 1024
#define N_BAT 8
#define BSS   (8ull*1024ull*1024ull)   // B*S*S elements per output

using bf16x8 = __attribute__((ext_vector_type(8))) short;
using f32x4  = __attribute__((ext_vector_type(4))) float;

__device__ __forceinline__ short f2bf(float v) {
    __hip_bfloat16 h = __float2bfloat16(v);
    return *reinterpret_cast<short*>(&h);
}

__device__ __forceinline__ void gload_lds16(const void* g, void* l) {
    __builtin_amdgcn_global_load_lds(
        (const __attribute__((address_space(1))) void*)g,
        (__attribute__((address_space(3))) void*)l, 16, 0, 0);
}

// ---------------------------------------------------------------------------
// 0) Bias rank-1 correction vectors: u = Wq^T bk, v = Wk^T bq, c0 = bq.bk
//    (exactly zero for this problem's inputs, but kept for correctness)
// ---------------------------------------------------------------------------
__global__ __launch_bounds__(256) void bias_vec_kernel(
    const float* __restrict__ Wq, const float* __restrict__ Wk,
    const float* __restrict__ bk, const float* __restrict__ bq,
    float* __restrict__ u, float* __restrict__ v, float* __restrict__ c0)
{
    __shared__ float sh[4];
    const int i = blockIdx.x * 256 + threadIdx.x;
    float au = 0.0f, av = 0.0f;
    for (int j = 0; j < 1024; ++j) {
        au += Wq[(size_t)j * 1024 + i] * bk[j];
        av += Wk[(size_t)j * 1024 + i] * bq[j];
    }
    u[i] = au;
    v[i] = av;
    if (blockIdx.x == 0) {
        const int t = threadIdx.x;
        float4 a = ((const float4*)bq)[t];
        float4 b = ((const float4*)bk)[t];
        float s = a.x*b.x + a.y*b.y + a.z*b.z + a.w*b.w;
        for (int off = 32; off > 0; off >>= 1) s += __shfl_down(s, off);
        const int lane = t & 63, w = t >> 6;
        if (lane == 0) sh[w] = s;
        __syncthreads();
        if (t == 0) c0[0] = sh[0] + sh[1] + sh[2] + sh[3];
    }
}

// ---------------------------------------------------------------------------
// 1) LayerNorm (unbiased std, eps added to std) -> bf16; also emits
//    p[row] = y.u and r2[row] = y.v (bias corrections for scores)
// ---------------------------------------------------------------------------
__global__ __launch_bounds__(256) void ln_kernel(
    const float* __restrict__ X, const float* __restrict__ gamma,
    const float* __restrict__ beta, const float* __restrict__ u,
    const float* __restrict__ v2, short* __restrict__ Y,
    float* __restrict__ p, float* __restrict__ r2)
{
    __shared__ float sh[16];
    const size_t row = blockIdx.x;
    const int t = threadIdx.x;
    float4 v = ((const float4*)(X + row * 1024))[t];
    float s  = v.x + v.y + v.z + v.w;
    float ss = v.x*v.x + v.y*v.y + v.z*v.z + v.w*v.w;
    for (int off = 32; off > 0; off >>= 1) {
        s  += __shfl_down(s, off);
        ss += __shfl_down(ss, off);
    }
    const int lane = t & 63, w = t >> 6;
    if (lane == 0) { sh[w] = s; sh[4 + w] = ss; }
    __syncthreads();
    if (t == 0) {
        float S  = sh[0] + sh[1] + sh[2] + sh[3];
        float SS = sh[4] + sh[5] + sh[6] + sh[7];
        float mu = S * (1.0f / 1024.0f);
        float var = fmaxf((SS - S * mu) * (1.0f / 1023.0f), 0.0f);
        sh[0] = mu;
        sh[1] = 1.0f / (sqrtf(var) + 1e-6f);
    }
    __syncthreads();
    const float mu = sh[0], inv = sh[1];
    float4 g  = ((const float4*)gamma)[t];
    float4 be = ((const float4*)beta)[t];
    float y0 = g.x * (v.x - mu) * inv + be.x;
    float y1 = g.y * (v.y - mu) * inv + be.y;
    float y2 = g.z * (v.z - mu) * inv + be.z;
    float y3 = g.w * (v.w - mu) * inv + be.w;
    short4 o;
    o.x = f2bf(y0); o.y = f2bf(y1); o.z = f2bf(y2); o.w = f2bf(y3);
    ((short4*)(Y + row * 1024))[t] = o;
    // bias-correction dots (u, v2 are tiny & L2-hot)
    float4 uu = ((const float4*)u)[t];
    float4 vv = ((const float4*)v2)[t];
    float dp = y0*uu.x + y1*uu.y + y2*uu.z + y3*uu.w;
    float dr = y0*vv.x + y1*vv.y + y2*vv.z + y3*vv.w;
    for (int off = 32; off > 0; off >>= 1) {
        dp += __shfl_down(dp, off);
        dr += __shfl_down(dr, off);
    }
    if (lane == 0) { sh[8 + w] = dp; sh[12 + w] = dr; }
    __syncthreads();
    if (t == 0) {
        p[row]  = sh[8] + sh[9] + sh[10] + sh[11];
        r2[row] = sh[12] + sh[13] + sh[14] + sh[15];
    }
}

// ---------------------------------------------------------------------------
// 2) Transpose + convert Wq, Wk (f32 [D][D]) -> bf16 transposed copies
//    Wqt[i][d] = Wq[d][i], Wkt likewise. 32x32 LDS tiles.
// ---------------------------------------------------------------------------
__global__ __launch_bounds__(256) void cvt_t_kernel(
    const float* __restrict__ Wq, const float* __restrict__ Wk,
    short* __restrict__ wqt, short* __restrict__ wkt)
{
    __shared__ float T[32][33];
    const float* src = blockIdx.z ? Wk : Wq;
    short* dst = blockIdx.z ? wkt : wqt;
    const int bi = blockIdx.x * 32, bj = blockIdx.y * 32;
    const int c = threadIdx.x & 31, r0 = threadIdx.x >> 5;
#pragma unroll
    for (int rr = 0; rr < 4; ++rr) {
        const int r = r0 + rr * 8;
        T[r][c] = src[(size_t)(bi + r) * 1024 + bj + c];
    }
    __syncthreads();
#pragma unroll
    for (int rr = 0; rr < 4; ++rr) {
        const int r = r0 + rr * 8;
        dst[(size_t)(bj + r) * 1024 + bi + c] = f2bf(T[c][r]);
    }
}

// ---------------------------------------------------------------------------
// 3) Generic bf16 GEMM: C[m][n] = sum_k A[m][k]*Bt[n][k] (+ bias[n]), bf16 out
//    m97-style 128x128 tile, BK=32, 4 waves. Strides fixed at 1024.
//    Used for M2T = Wkt @ Wqt^T (grid 8x8) and t = xb @ M2T^T (grid 64x8).
// ---------------------------------------------------------------------------
__global__ __launch_bounds__(256) void gemm_bf16(
    const short* __restrict__ A, const short* __restrict__ Bt,
    const float* __restrict__ bias, short* __restrict__ C)
{
    __shared__ short As[128 * 32];
    __shared__ short Bs[128 * 32];
    const int tid  = threadIdx.x;
    const int lane = tid & 63;
    const int w    = tid >> 6;
    const int wr   = w >> 1, wc = w & 1;
    const int brow = blockIdx.x * 128;
    const int bcol = blockIdx.y * 128;

    f32x4 acc[4][4];
#pragma unroll
    for (int m = 0; m < 4; ++m)
#pragma unroll
        for (int n = 0; n < 4; ++n) acc[m][n] = 0.0f;

    for (int k0 = 0; k0 < 1024; k0 += 32) {
#pragma unroll
        for (int c = 0; c < 2; ++c) {
            const int base = w * 2048 + c * 1024;
            const int chunk = base + lane * 16;      // byte offset in 8KB tile
            const int row = chunk >> 6;              // 64 B per 32-elem row
            const int col = (chunk & 63) >> 1;       // bf16 col (0,8,16,24)
            gload_lds16(A  + (size_t)(brow + row) * 1024 + (k0 + col),
                        (char*)As + base);
            gload_lds16(Bt + (size_t)(bcol + row) * 1024 + (k0 + col),
                        (char*)Bs + base);
        }
        __syncthreads();
        bf16x8 af[4], bfr[4];
        const int rsel = lane & 15;
        const int ksel = (lane >> 4) * 8;
#pragma unroll
        for (int m = 0; m < 4; ++m)
            af[m] = *(const bf16x8*)&As[(wr * 64 + m * 16 + rsel) * 32 + ksel];
#pragma unroll
        for (int n = 0; n < 4; ++n)
            bfr[n] = *(const bf16x8*)&Bs[(wc * 64 + n * 16 + rsel) * 32 + ksel];
#pragma unroll
        for (int m = 0; m < 4; ++m)
#pragma unroll
            for (int n = 0; n < 4; ++n)
                acc[m][n] = __builtin_amdgcn_mfma_f32_16x16x32_bf16(
                    af[m], bfr[n], acc[m][n], 0, 0, 0);
        __syncthreads();
    }
#pragma unroll
    for (int m = 0; m < 4; ++m)
#pragma unroll
        for (int n = 0; n < 4; ++n) {
            const int colg = bcol + wc * 64 + n * 16 + (lane & 15);
            const float bv = bias ? bias[colg] : 0.0f;
#pragma unroll
            for (int r = 0; r < 4; ++r) {
                const int rowg = brow + wr * 64 + m * 16 + ((lane >> 4) * 4 + r);
                C[(size_t)rowg * 1024 + colg] = f2bf(acc[m][n][r] + bv);
            }
        }
}

// ---------------------------------------------------------------------------
// 4) Scores GEMM (per batch): Sc[q][k] = (t[q].x[k] + p[q] + r[k] + c0)/512
// ---------------------------------------------------------------------------
__global__ __launch_bounds__(256) void gemm_scores(
    const short* __restrict__ Tm, const short* __restrict__ Xm,
    const float* __restrict__ p, const float* __restrict__ r2,
    const float* __restrict__ c0p, float* __restrict__ Sc)
{
    __shared__ short As[128 * 32];
    __shared__ short Bs[128 * 32];
    const int b = blockIdx.z;
    const short* A  = Tm + (size_t)b * 1024 * 1024;
    const short* Bt = Xm + (size_t)b * 1024 * 1024;
    const float* pb = p  + (size_t)b * 1024;
    const float* rb = r2 + (size_t)b * 1024;
    float* C = Sc + (size_t)b * 1024 * 1024;

    const int tid  = threadIdx.x;
    const int lane = tid & 63;
    const int w    = tid >> 6;
    const int wr   = w >> 1, wc = w & 1;
    const int brow = blockIdx.x * 128;
    const int bcol = blockIdx.y * 128;

    f32x4 acc[4][4];
#pragma unroll
    for (int m = 0; m < 4; ++m)
#pragma unroll
        for (int n = 0; n < 4; ++n) acc[m][n] = 0.0f;

    for (int k0 = 0; k0 < 1024; k0 += 32) {
#pragma unroll
        for (int c = 0; c < 2; ++c) {
            const int base = w * 2048 + c * 1024;
            const int chunk = base + lane * 16;
            const int row = chunk >> 6;
            const int col = (chunk & 63) >> 1;
            gload_lds16(A  + (size_t)(brow + row) * 1024 + (k0 + col),
                        (char*)As + base);
            gload_lds16(Bt + (size_t)(bcol + row) * 1024 + (k0 + col),
                        (char*)Bs + base);
        }
        __syncthreads();
        bf16x8 af[4], bfr[4];
        const int rsel = lane & 15;
        const int ksel = (lane >> 4) * 8;
#pragma unroll
        for (int m = 0; m < 4; ++m)
            af[m] = *(const bf16x8*)&As[(wr * 64 + m * 16 + rsel) * 32 + ksel];
#pragma unroll
        for (int n = 0; n < 4; ++n)
            bfr[n] = *(const bf16x8*)&Bs[(wc * 64 + n * 16 + rsel) * 32 + ksel];
#pragma unroll
        for (int m = 0; m < 4; ++m)
#pragma unroll
            for (int n = 0; n < 4; ++n)
                acc[m][n] = __builtin_amdgcn_mfma_f32_16x16x32_bf16(
                    af[m], bfr[n], acc[m][n], 0, 0, 0);
        __syncthreads();
    }
    const float c0v = c0p[0];
#pragma unroll
    for (int m = 0; m < 4; ++m)
#pragma unroll
        for (int n = 0; n < 4; ++n) {
            const int colg = bcol + wc * 64 + n * 16 + (lane & 15);
            const float radd = rb[colg] + c0v;
#pragma unroll
            for (int r = 0; r < 4; ++r) {
                const int rowg = brow + wr * 64 + m * 16 + ((lane >> 4) * 4 + r);
                C[(size_t)rowg * 1024 + colg] =
                    (acc[m][n][r] + pb[rowg] + radd) * 0.001953125f; // /512
            }
        }
}

// ---------------------------------------------------------------------------
// 5) Masked row softmax: block per (b,q) row
// ---------------------------------------------------------------------------
__global__ __launch_bounds__(256) void softmax_kernel(
    const float* __restrict__ Sc, const int* __restrict__ adj,
    float* __restrict__ At)
{
    __shared__ float sh[4];
    const size_t row = blockIdx.x;
    const int t = threadIdx.x;
    const float4 sv = ((const float4*)(Sc + row * 1024))[t];
    const int4   av = ((const int4*)(adj + row * 1024))[t];
    float m = -3.0e38f;
    if (av.x) m = fmaxf(m, sv.x);
    if (av.y) m = fmaxf(m, sv.y);
    if (av.z) m = fmaxf(m, sv.z);
    if (av.w) m = fmaxf(m, sv.w);
    for (int off = 32; off > 0; off >>= 1) m = fmaxf(m, __shfl_down(m, off));
    const int lane = t & 63, w = t >> 6;
    if (lane == 0) sh[w] = m;
    __syncthreads();
    const float M = fmaxf(fmaxf(sh[0], sh[1]), fmaxf(sh[2], sh[3]));
    __syncthreads();
    float e0 = av.x ? expf(sv.x - M) : 0.0f;
    float e1 = av.y ? expf(sv.y - M) : 0.0f;
    float e2 = av.z ? expf(sv.z - M) : 0.0f;
    float e3 = av.w ? expf(sv.w - M) : 0.0f;
    float s = e0 + e1 + e2 + e3;
    for (int off = 32; off > 0; off >>= 1) s += __shfl_down(s, off);
    if (lane == 0) sh[w] = s;
    __syncthreads();
    const float Sm = sh[0] + sh[1] + sh[2] + sh[3];
    float4 o;
    if (Sm > 0.0f) {
        const float inv = 1.0f / Sm;
        o.x = e0 * inv; o.y = e1 * inv; o.z = e2 * inv; o.w = e3 * inv;
    } else {  // all-masked row: jax softmax of equal values -> uniform
        o.x = o.y = o.z = o.w = 1.0f / 1024.0f;
    }
    ((float4*)(At + row * 1024))[t] = o;
}

// ---------------------------------------------------------------------------
// 6) Prefix sums of L[k]=log(na[k,k+1]+1e-9) per batch, computed DIRECTLY
//    from attn (na recomputed on the fly). f64 Hillis-Steele scan in LDS.
// ---------------------------------------------------------------------------
__global__ __launch_bounds__(1024) void cum2_kernel(
    const float* __restrict__ At, const float* __restrict__ prior_p,
    double* __restrict__ cum)
{
    __shared__ double sh[1024];
    const int b = blockIdx.x;
    const int t = threadIdx.x;
    const float prior = *prior_p;
    const float om = 1.0f - prior;
    const float* attn = At + (size_t)b * 1024 * 1024;
    double v = 0.0;
    if (t >= 1) {
        const int k = t - 1;   // superdiagonal element na[k][k+1]
        const float a1 = attn[(size_t)k * 1024 + (k + 1)];
        const float a2 = attn[(size_t)(k + 1) * 1024 + k];
        const float na = prior + om * sqrtf(a1 * a2 + 1e-9f);
        v = (double)logf(na + 1e-9f);
    }
    sh[t] = v;
    __syncthreads();
#pragma unroll
    for (int off = 1; off < 1024; off <<= 1) {
        const double add = (t >= off) ? sh[t - off] : 0.0;
        __syncthreads();
        sh[t] += add;
        __syncthreads();
    }
    cum[b * 1024 + t] = sh[t];
}

// ---------------------------------------------------------------------------
// 7) Fused: na = prior+(1-prior)*sqrt(attn*attn^T+1e-9) (in place) AND
//    g_attn fill (diag -> na[i,i]; off-diag -> exp(cum[hi]-cum[lo])+1e-9).
//    Block handles a 32x32 tile-pair (ti<=tj).
// ---------------------------------------------------------------------------
__global__ __launch_bounds__(256) void na_g_kernel(
    float* __restrict__ At, const float* __restrict__ prior_p,
    const double* __restrict__ cum, float* __restrict__ G)
{
    const int ti = blockIdx.x >> 5, tj = blockIdx.x & 31;
    if (tj < ti) return;
    const int b = blockIdx.y;
    const float prior = *prior_p;
    const float om = 1.0f - prior;
    float* base = At + (size_t)b * 1024 * 1024;
    float* gb   = G  + (size_t)b * 1024 * 1024;
    const double* cb = cum + (size_t)b * 1024;
    __shared__ float T1[32][33];
    __shared__ float T2[32][33];
    const int c = threadIdx.x & 31, r0 = threadIdx.x >> 5;
#pragma unroll
    for (int rr = 0; rr < 4; ++rr) {
        const int r = r0 + rr * 8;
        T1[r][c] = base[(size_t)(ti * 32 + r) * 1024 + tj * 32 + c];
        T2[r][c] = base[(size_t)(tj * 32 + r) * 1024 + ti * 32 + c];
    }
    __syncthreads();
#pragma unroll
    for (int rr = 0; rr < 4; ++rr) {
        const int r = r0 + rr * 8;
        // side 1: (ti, tj) tile, element (R1, C1)
        const int R1 = ti * 32 + r, C1 = tj * 32 + c;
        const float na1 = prior + om * sqrtf(T1[r][c] * T2[c][r] + 1e-9f);
        base[(size_t)R1 * 1024 + C1] = na1;
        float g1;
        if (R1 == C1) g1 = na1;
        else {
            const int lo = min(R1, C1), hi = max(R1, C1);
            g1 = expf((float)(cb[hi] - cb[lo])) + 1e-9f;
        }
        gb[(size_t)R1 * 1024 + C1] = g1;
        // side 2: (tj, ti) tile, element (R2, C2)
        const int R2 = tj * 32 + r, C2 = ti * 32 + c;
        const float na2 = prior + om * sqrtf(T2[r][c] * T1[c][r] + 1e-9f);
        base[(size_t)R2 * 1024 + C2] = na2;
        float g2;
        if (R2 == C2) g2 = na2;
        else {
            const int lo = min(R2, C2), hi = max(R2, C2);
            g2 = expf((float)(cb[hi] - cb[lo])) + 1e-9f;
        }
        gb[(size_t)R2 * 1024 + C2] = g2;
    }
}

// ---------------------------------------------------------------------------
extern "C" void kernel_launch(void* const* d_in, const int* in_sizes, int n_in,
                              void* d_out, int out_size, void* d_ws, size_t ws_size,
                              hipStream_t stream)
{
    const float* context = (const float*)d_in[0];
    // d_in[1] = eos_mask (unused by reference)
    const float* prior   = (const float*)d_in[2];
    const int*   adj     = (const int*)d_in[3];
    const float* Wk      = (const float*)d_in[4];
    const float* bk      = (const float*)d_in[5];
    const float* Wq      = (const float*)d_in[6];
    const float* bq      = (const float*)d_in[7];
    const float* gamma   = (const float*)d_in[8];
    const float* beta    = (const float*)d_in[9];

    float* out   = (float*)d_out;
    float* gout  = out;          // first output: g_attn (scores scratch first)
    float* naout = out + BSS;    // second output: neibor_attn (attn in-place)

    // workspace layout (~39 MB)
    char* ws = (char*)d_ws;
    short*  xb   = (short*)(ws);                        // 16 MB  x (bf16)
    short*  wqt  = (short*)(ws + (16ull << 20));        //  2 MB  Wq^T (bf16)
    short*  wkt  = (short*)(ws + (18ull << 20));        //  2 MB  Wk^T (bf16)
    short*  m2t  = (short*)(ws + (20ull << 20));        //  2 MB  (Wq^T Wk)^T
    short*  tb   = (short*)(ws + (22ull << 20));        // 16 MB  t = x@M2
    double* cumd = (double*)(ws + (38ull << 20));       // 64 KB
    float*  uvec = (float*)(ws + (38ull << 20) + (1ull << 16)); // 4 KB
    float*  vvec = uvec + 1024;                         // 4 KB
    float*  c0   = vvec + 1024;                         // 4 B
    float*  pvec = c0 + 64;                             // 32 KB (8192 f32)
    float*  rvec = pvec + 8192;                         // 32 KB

    bias_vec_kernel<<<4, 256, 0, stream>>>(Wq, Wk, bk, bq, uvec, vvec, c0);
    ln_kernel<<<8192, 256, 0, stream>>>(context, gamma, beta, uvec, vvec,
                                        xb, pvec, rvec);
    cvt_t_kernel<<<dim3(32, 32, 2), 256, 0, stream>>>(Wq, Wk, wqt, wkt);
    // M2T[j][i] = sum_d Wkt[j][d] * Wqt[i][d]  ( = (Wq^T Wk)[i][j] )
    gemm_bf16<<<dim3(8, 8), 256, 0, stream>>>(wkt, wqt, nullptr, m2t);
    // t[q][j] = sum_i xb[q][i] * M2T[j][i]
    gemm_bf16<<<dim3(64, 8), 256, 0, stream>>>(xb, m2t, nullptr, tb);
    // scores[b][q][k] = (t[q].x[k] + p[q] + r[k] + c0) / 512
    gemm_scores<<<dim3(8, 8, 8), 256, 0, stream>>>(tb, xb, pvec, rvec, c0, gout);
    softmax_kernel<<<8192, 256, 0, stream>>>(gout, adj, naout);
    cum2_kernel<<<8, 1024, 0, stream>>>(naout, prior, cumd);
    na_g_kernel<<<dim3(1024, 8), 256, 0, stream>>>(naout, prior, cumd, gout);
}

// Round 4
// 157.921 us; speedup vs baseline: 1.3138x; 1.3138x over previous
//
#include <hip/hip_runtime.h>
#include <hip/hip_bf16.h>

// Shapes (fixed for this problem)
#define S_LEN 1024
#define D_DIM 1024
#define N_BAT 8
#define BSS   (8ull*1024ull*1024ull)   // B*S*S elements per output

using bf16x8 = __attribute__((ext_vector_type(8))) short;
using f32x4  = __attribute__((ext_vector_type(4))) float;

__device__ __forceinline__ short f2bf(float v) {
    __hip_bfloat16 h = __float2bfloat16(v);
    return *reinterpret_cast<short*>(&h);
}

__device__ __forceinline__ void gload_lds16(const void* g, void* l) {
    __builtin_amdgcn_global_load_lds(
        (const __attribute__((address_space(1))) void*)g,
        (__attribute__((address_space(3))) void*)l, 16, 0, 0);
}

// ---------------------------------------------------------------------------
// 0a) Bias GEMV stage 1: partial sums of u = Wq^T bk, v = Wk^T bq.
//     grid (8 col-chunks, 16 row-chunks) x 256 threads; coalesced float4 rows.
// ---------------------------------------------------------------------------
__global__ __launch_bounds__(256) void bias_gemv1(
    const float* __restrict__ Wq, const float* __restrict__ Wk,
    const float* __restrict__ bk, const float* __restrict__ bq,
    float* __restrict__ pu, float* __restrict__ pv)
{
    __shared__ float su[8][128];
    __shared__ float sv[8][128];
    const int tx = threadIdx.x & 31;        // column group (float4)
    const int ty = threadIdx.x >> 5;        // 0..7 row subgroup
    const int colBase = blockIdx.x * 128;
    const int rowBase = blockIdx.y * 64;
    const int i = colBase + tx * 4;
    float4 au = {0,0,0,0}, av = {0,0,0,0};
#pragma unroll
    for (int jj = 0; jj < 8; ++jj) {
        const int j = rowBase + ty + jj * 8;
        const float bkv = bk[j], bqv = bq[j];
        const float4 wq = *(const float4*)&Wq[(size_t)j * 1024 + i];
        const float4 wk = *(const float4*)&Wk[(size_t)j * 1024 + i];
        au.x += wq.x * bkv; au.y += wq.y * bkv; au.z += wq.z * bkv; au.w += wq.w * bkv;
        av.x += wk.x * bqv; av.y += wk.y * bqv; av.z += wk.z * bqv; av.w += wk.w * bqv;
    }
    ((float4*)su[ty])[tx] = au;
    ((float4*)sv[ty])[tx] = av;
    __syncthreads();
    if (ty == 0) {
        float4 s1 = ((float4*)su[0])[tx];
        float4 s2 = ((float4*)sv[0])[tx];
#pragma unroll
        for (int k = 1; k < 8; ++k) {
            const float4 t1 = ((float4*)su[k])[tx];
            const float4 t2 = ((float4*)sv[k])[tx];
            s1.x += t1.x; s1.y += t1.y; s1.z += t1.z; s1.w += t1.w;
            s2.x += t2.x; s2.y += t2.y; s2.z += t2.z; s2.w += t2.w;
        }
        ((float4*)&pu[(size_t)blockIdx.y * 1024 + colBase])[tx] = s1;
        ((float4*)&pv[(size_t)blockIdx.y * 1024 + colBase])[tx] = s2;
    }
}

// ---------------------------------------------------------------------------
// 0b) Bias GEMV stage 2: reduce 16 partials per column; also c0 = bq.bk
// ---------------------------------------------------------------------------
__global__ __launch_bounds__(256) void bias_gemv2(
    const float* __restrict__ pu, const float* __restrict__ pv,
    const float* __restrict__ bk, const float* __restrict__ bq,
    float* __restrict__ u, float* __restrict__ v, float* __restrict__ c0)
{
    __shared__ float sh[4];
    const int i = blockIdx.x * 256 + threadIdx.x;
    float su = 0.0f, sv = 0.0f;
#pragma unroll
    for (int k = 0; k < 16; ++k) {
        su += pu[k * 1024 + i];
        sv += pv[k * 1024 + i];
    }
    u[i] = su;
    v[i] = sv;
    if (blockIdx.x == 0) {
        const int t = threadIdx.x;
        const float4 a = ((const float4*)bq)[t];
        const float4 b = ((const float4*)bk)[t];
        float s = a.x*b.x + a.y*b.y + a.z*b.z + a.w*b.w;
        for (int off = 32; off > 0; off >>= 1) s += __shfl_down(s, off);
        const int lane = t & 63, w = t >> 6;
        if (lane == 0) sh[w] = s;
        __syncthreads();
        if (t == 0) c0[0] = sh[0] + sh[1] + sh[2] + sh[3];
    }
}

// ---------------------------------------------------------------------------
// 1) LayerNorm (unbiased std, eps added to std) -> bf16; also emits
//    p[row] = y.u and r2[row] = y.v (bias corrections for scores)
// ---------------------------------------------------------------------------
__global__ __launch_bounds__(256) void ln_kernel(
    const float* __restrict__ X, const float* __restrict__ gamma,
    const float* __restrict__ beta, const float* __restrict__ u,
    const float* __restrict__ v2, short* __restrict__ Y,
    float* __restrict__ p, float* __restrict__ r2)
{
    __shared__ float sh[16];
    const size_t row = blockIdx.x;
    const int t = threadIdx.x;
    float4 v = ((const float4*)(X + row * 1024))[t];
    float s  = v.x + v.y + v.z + v.w;
    float ss = v.x*v.x + v.y*v.y + v.z*v.z + v.w*v.w;
    for (int off = 32; off > 0; off >>= 1) {
        s  += __shfl_down(s, off);
        ss += __shfl_down(ss, off);
    }
    const int lane = t & 63, w = t >> 6;
    if (lane == 0) { sh[w] = s; sh[4 + w] = ss; }
    __syncthreads();
    if (t == 0) {
        float S  = sh[0] + sh[1] + sh[2] + sh[3];
        float SS = sh[4] + sh[5] + sh[6] + sh[7];
        float mu = S * (1.0f / 1024.0f);
        float var = fmaxf((SS - S * mu) * (1.0f / 1023.0f), 0.0f);
        sh[0] = mu;
        sh[1] = 1.0f / (sqrtf(var) + 1e-6f);
    }
    __syncthreads();
    const float mu = sh[0], inv = sh[1];
    float4 g  = ((const float4*)gamma)[t];
    float4 be = ((const float4*)beta)[t];
    float y0 = g.x * (v.x - mu) * inv + be.x;
    float y1 = g.y * (v.y - mu) * inv + be.y;
    float y2 = g.z * (v.z - mu) * inv + be.z;
    float y3 = g.w * (v.w - mu) * inv + be.w;
    short4 o;
    o.x = f2bf(y0); o.y = f2bf(y1); o.z = f2bf(y2); o.w = f2bf(y3);
    ((short4*)(Y + row * 1024))[t] = o;
    // bias-correction dots (u, v2 are tiny & L2-hot)
    float4 uu = ((const float4*)u)[t];
    float4 vv = ((const float4*)v2)[t];
    float dp = y0*uu.x + y1*uu.y + y2*uu.z + y3*uu.w;
    float dr = y0*vv.x + y1*vv.y + y2*vv.z + y3*vv.w;
    for (int off = 32; off > 0; off >>= 1) {
        dp += __shfl_down(dp, off);
        dr += __shfl_down(dr, off);
    }
    if (lane == 0) { sh[8 + w] = dp; sh[12 + w] = dr; }
    __syncthreads();
    if (t == 0) {
        p[row]  = sh[8] + sh[9] + sh[10] + sh[11];
        r2[row] = sh[12] + sh[13] + sh[14] + sh[15];
    }
}

// ---------------------------------------------------------------------------
// 2) Transpose + convert Wq, Wk (f32 [D][D]) -> bf16 transposed copies
//    Wqt[i][d] = Wq[d][i], Wkt likewise. 32x32 LDS tiles.
// ---------------------------------------------------------------------------
__global__ __launch_bounds__(256) void cvt_t_kernel(
    const float* __restrict__ Wq, const float* __restrict__ Wk,
    short* __restrict__ wqt, short* __restrict__ wkt)
{
    __shared__ float T[32][33];
    const float* src = blockIdx.z ? Wk : Wq;
    short* dst = blockIdx.z ? wkt : wqt;
    const int bi = blockIdx.x * 32, bj = blockIdx.y * 32;
    const int c = threadIdx.x & 31, r0 = threadIdx.x >> 5;
#pragma unroll
    for (int rr = 0; rr < 4; ++rr) {
        const int r = r0 + rr * 8;
        T[r][c] = src[(size_t)(bi + r) * 1024 + bj + c];
    }
    __syncthreads();
#pragma unroll
    for (int rr = 0; rr < 4; ++rr) {
        const int r = r0 + rr * 8;
        dst[(size_t)(bj + r) * 1024 + bi + c] = f2bf(T[c][r]);
    }
}

// ---------------------------------------------------------------------------
// 3) Generic bf16 GEMM: C[m][n] = sum_k A[m][k]*Bt[n][k] (+ bias[n]), bf16 out
//    m97-style 128x128 tile, BK=32, 4 waves. Strides fixed at 1024.
//    Used for M2T = Wkt @ Wqt^T (grid 8x8) and t = xb @ M2T^T (grid 64x8).
// ---------------------------------------------------------------------------
__global__ __launch_bounds__(256) void gemm_bf16(
    const short* __restrict__ A, const short* __restrict__ Bt,
    const float* __restrict__ bias, short* __restrict__ C)
{
    __shared__ short As[128 * 32];
    __shared__ short Bs[128 * 32];
    const int tid  = threadIdx.x;
    const int lane = tid & 63;
    const int w    = tid >> 6;
    const int wr   = w >> 1, wc = w & 1;
    const int brow = blockIdx.x * 128;
    const int bcol = blockIdx.y * 128;

    f32x4 acc[4][4];
#pragma unroll
    for (int m = 0; m < 4; ++m)
#pragma unroll
        for (int n = 0; n < 4; ++n) acc[m][n] = 0.0f;

    for (int k0 = 0; k0 < 1024; k0 += 32) {
#pragma unroll
        for (int c = 0; c < 2; ++c) {
            const int base = w * 2048 + c * 1024;
            const int chunk = base + lane * 16;      // byte offset in 8KB tile
            const int row = chunk >> 6;              // 64 B per 32-elem row
            const int col = (chunk & 63) >> 1;       // bf16 col (0,8,16,24)
            gload_lds16(A  + (size_t)(brow + row) * 1024 + (k0 + col),
                        (char*)As + base);
            gload_lds16(Bt + (size_t)(bcol + row) * 1024 + (k0 + col),
                        (char*)Bs + base);
        }
        __syncthreads();
        bf16x8 af[4], bfr[4];
        const int rsel = lane & 15;
        const int ksel = (lane >> 4) * 8;
#pragma unroll
        for (int m = 0; m < 4; ++m)
            af[m] = *(const bf16x8*)&As[(wr * 64 + m * 16 + rsel) * 32 + ksel];
#pragma unroll
        for (int n = 0; n < 4; ++n)
            bfr[n] = *(const bf16x8*)&Bs[(wc * 64 + n * 16 + rsel) * 32 + ksel];
#pragma unroll
        for (int m = 0; m < 4; ++m)
#pragma unroll
            for (int n = 0; n < 4; ++n)
                acc[m][n] = __builtin_amdgcn_mfma_f32_16x16x32_bf16(
                    af[m], bfr[n], acc[m][n], 0, 0, 0);
        __syncthreads();
    }
#pragma unroll
    for (int m = 0; m < 4; ++m)
#pragma unroll
        for (int n = 0; n < 4; ++n) {
            const int colg = bcol + wc * 64 + n * 16 + (lane & 15);
            const float bv = bias ? bias[colg] : 0.0f;
#pragma unroll
            for (int r = 0; r < 4; ++r) {
                const int rowg = brow + wr * 64 + m * 16 + ((lane >> 4) * 4 + r);
                C[(size_t)rowg * 1024 + colg] = f2bf(acc[m][n][r] + bv);
            }
        }
}

// ---------------------------------------------------------------------------
// 4) Scores GEMM (per batch): Sc[q][k] = (t[q].x[k] + p[q] + r[k] + c0)/512
// ---------------------------------------------------------------------------
__global__ __launch_bounds__(256) void gemm_scores(
    const short* __restrict__ Tm, const short* __restrict__ Xm,
    const float* __restrict__ p, const float* __restrict__ r2,
    const float* __restrict__ c0p, float* __restrict__ Sc)
{
    __shared__ short As[128 * 32];
    __shared__ short Bs[128 * 32];
    const int b = blockIdx.z;
    const short* A  = Tm + (size_t)b * 1024 * 1024;
    const short* Bt = Xm + (size_t)b * 1024 * 1024;
    const float* pb = p  + (size_t)b * 1024;
    const float* rb = r2 + (size_t)b * 1024;
    float* C = Sc + (size_t)b * 1024 * 1024;

    const int tid  = threadIdx.x;
    const int lane = tid & 63;
    const int w    = tid >> 6;
    const int wr   = w >> 1, wc = w & 1;
    const int brow = blockIdx.x * 128;
    const int bcol = blockIdx.y * 128;

    f32x4 acc[4][4];
#pragma unroll
    for (int m = 0; m < 4; ++m)
#pragma unroll
        for (int n = 0; n < 4; ++n) acc[m][n] = 0.0f;

    for (int k0 = 0; k0 < 1024; k0 += 32) {
#pragma unroll
        for (int c = 0; c < 2; ++c) {
            const int base = w * 2048 + c * 1024;
            const int chunk = base + lane * 16;
            const int row = chunk >> 6;
            const int col = (chunk & 63) >> 1;
            gload_lds16(A  + (size_t)(brow + row) * 1024 + (k0 + col),
                        (char*)As + base);
            gload_lds16(Bt + (size_t)(bcol + row) * 1024 + (k0 + col),
                        (char*)Bs + base);
        }
        __syncthreads();
        bf16x8 af[4], bfr[4];
        const int rsel = lane & 15;
        const int ksel = (lane >> 4) * 8;
#pragma unroll
        for (int m = 0; m < 4; ++m)
            af[m] = *(const bf16x8*)&As[(wr * 64 + m * 16 + rsel) * 32 + ksel];
#pragma unroll
        for (int n = 0; n < 4; ++n)
            bfr[n] = *(const bf16x8*)&Bs[(wc * 64 + n * 16 + rsel) * 32 + ksel];
#pragma unroll
        for (int m = 0; m < 4; ++m)
#pragma unroll
            for (int n = 0; n < 4; ++n)
                acc[m][n] = __builtin_amdgcn_mfma_f32_16x16x32_bf16(
                    af[m], bfr[n], acc[m][n], 0, 0, 0);
        __syncthreads();
    }
    const float c0v = c0p[0];
#pragma unroll
    for (int m = 0; m < 4; ++m)
#pragma unroll
        for (int n = 0; n < 4; ++n) {
            const int colg = bcol + wc * 64 + n * 16 + (lane & 15);
            const float radd = rb[colg] + c0v;
#pragma unroll
            for (int r = 0; r < 4; ++r) {
                const int rowg = brow + wr * 64 + m * 16 + ((lane >> 4) * 4 + r);
                C[(size_t)rowg * 1024 + colg] =
                    (acc[m][n][r] + pb[rowg] + radd) * 0.001953125f; // /512
            }
        }
}

// ---------------------------------------------------------------------------
// 5) Masked row softmax: block per (b,q) row
// ---------------------------------------------------------------------------
__global__ __launch_bounds__(256) void softmax_kernel(
    const float* __restrict__ Sc, const int* __restrict__ adj,
    float* __restrict__ At)
{
    __shared__ float sh[4];
    const size_t row = blockIdx.x;
    const int t = threadIdx.x;
    const float4 sv = ((const float4*)(Sc + row * 1024))[t];
    const int4   av = ((const int4*)(adj + row * 1024))[t];
    float m = -3.0e38f;
    if (av.x) m = fmaxf(m, sv.x);
    if (av.y) m = fmaxf(m, sv.y);
    if (av.z) m = fmaxf(m, sv.z);
    if (av.w) m = fmaxf(m, sv.w);
    for (int off = 32; off > 0; off >>= 1) m = fmaxf(m, __shfl_down(m, off));
    const int lane = t & 63, w = t >> 6;
    if (lane == 0) sh[w] = m;
    __syncthreads();
    const float M = fmaxf(fmaxf(sh[0], sh[1]), fmaxf(sh[2], sh[3]));
    __syncthreads();
    float e0 = av.x ? expf(sv.x - M) : 0.0f;
    float e1 = av.y ? expf(sv.y - M) : 0.0f;
    float e2 = av.z ? expf(sv.z - M) : 0.0f;
    float e3 = av.w ? expf(sv.w - M) : 0.0f;
    float s = e0 + e1 + e2 + e3;
    for (int off = 32; off > 0; off >>= 1) s += __shfl_down(s, off);
    if (lane == 0) sh[w] = s;
    __syncthreads();
    const float Sm = sh[0] + sh[1] + sh[2] + sh[3];
    float4 o;
    if (Sm > 0.0f) {
        const float inv = 1.0f / Sm;
        o.x = e0 * inv; o.y = e1 * inv; o.z = e2 * inv; o.w = e3 * inv;
    } else {  // all-masked row: jax softmax of equal values -> uniform
        o.x = o.y = o.z = o.w = 1.0f / 1024.0f;
    }
    ((float4*)(At + row * 1024))[t] = o;
}

// ---------------------------------------------------------------------------
// 6) Prefix sums of L[k]=log(na[k,k+1]+1e-9) per batch, computed DIRECTLY
//    from attn (na recomputed on the fly). f64 Hillis-Steele scan in LDS.
// ---------------------------------------------------------------------------
__global__ __launch_bounds__(1024) void cum2_kernel(
    const float* __restrict__ At, const float* __restrict__ prior_p,
    double* __restrict__ cum)
{
    __shared__ double sh[1024];
    const int b = blockIdx.x;
    const int t = threadIdx.x;
    const float prior = *prior_p;
    const float om = 1.0f - prior;
    const float* attn = At + (size_t)b * 1024 * 1024;
    double v = 0.0;
    if (t >= 1) {
        const int k = t - 1;   // superdiagonal element na[k][k+1]
        const float a1 = attn[(size_t)k * 1024 + (k + 1)];
        const float a2 = attn[(size_t)(k + 1) * 1024 + k];
        const float na = prior + om * sqrtf(a1 * a2 + 1e-9f);
        v = (double)logf(na + 1e-9f);
    }
    sh[t] = v;
    __syncthreads();
#pragma unroll
    for (int off = 1; off < 1024; off <<= 1) {
        const double add = (t >= off) ? sh[t - off] : 0.0;
        __syncthreads();
        sh[t] += add;
        __syncthreads();
    }
    cum[b * 1024 + t] = sh[t];
}

// ---------------------------------------------------------------------------
// 7) Fused: na = prior+(1-prior)*sqrt(attn*attn^T+1e-9) (in place) AND
//    g_attn fill (diag -> na[i,i]; off-diag -> exp(cum[hi]-cum[lo])+1e-9).
//    Block handles a 32x32 tile-pair (ti<=tj).
// ---------------------------------------------------------------------------
__global__ __launch_bounds__(256) void na_g_kernel(
    float* __restrict__ At, const float* __restrict__ prior_p,
    const double* __restrict__ cum, float* __restrict__ G)
{
    const int ti = blockIdx.x >> 5, tj = blockIdx.x & 31;
    if (tj < ti) return;
    const int b = blockIdx.y;
    const float prior = *prior_p;
    const float om = 1.0f - prior;
    float* base = At + (size_t)b * 1024 * 1024;
    float* gb   = G  + (size_t)b * 1024 * 1024;
    const double* cb = cum + (size_t)b * 1024;
    __shared__ float T1[32][33];
    __shared__ float T2[32][33];
    const int c = threadIdx.x & 31, r0 = threadIdx.x >> 5;
#pragma unroll
    for (int rr = 0; rr < 4; ++rr) {
        const int r = r0 + rr * 8;
        T1[r][c] = base[(size_t)(ti * 32 + r) * 1024 + tj * 32 + c];
        T2[r][c] = base[(size_t)(tj * 32 + r) * 1024 + ti * 32 + c];
    }
    __syncthreads();
#pragma unroll
    for (int rr = 0; rr < 4; ++rr) {
        const int r = r0 + rr * 8;
        // side 1: (ti, tj) tile, element (R1, C1)
        const int R1 = ti * 32 + r, C1 = tj * 32 + c;
        const float na1 = prior + om * sqrtf(T1[r][c] * T2[c][r] + 1e-9f);
        base[(size_t)R1 * 1024 + C1] = na1;
        float g1;
        if (R1 == C1) g1 = na1;
        else {
            const int lo = min(R1, C1), hi = max(R1, C1);
            g1 = expf((float)(cb[hi] - cb[lo])) + 1e-9f;
        }
        gb[(size_t)R1 * 1024 + C1] = g1;
        // side 2: (tj, ti) tile, element (R2, C2)
        const int R2 = tj * 32 + r, C2 = ti * 32 + c;
        const float na2 = prior + om * sqrtf(T2[r][c] * T1[c][r] + 1e-9f);
        base[(size_t)R2 * 1024 + C2] = na2;
        float g2;
        if (R2 == C2) g2 = na2;
        else {
            const int lo = min(R2, C2), hi = max(R2, C2);
            g2 = expf((float)(cb[hi] - cb[lo])) + 1e-9f;
        }
        gb[(size_t)R2 * 1024 + C2] = g2;
    }
}

// ---------------------------------------------------------------------------
extern "C" void kernel_launch(void* const* d_in, const int* in_sizes, int n_in,
                              void* d_out, int out_size, void* d_ws, size_t ws_size,
                              hipStream_t stream)
{
    const float* context = (const float*)d_in[0];
    // d_in[1] = eos_mask (unused by reference)
    const float* prior   = (const float*)d_in[2];
    const int*   adj     = (const int*)d_in[3];
    const float* Wk      = (const float*)d_in[4];
    const float* bk      = (const float*)d_in[5];
    const float* Wq      = (const float*)d_in[6];
    const float* bq      = (const float*)d_in[7];
    const float* gamma   = (const float*)d_in[8];
    const float* beta    = (const float*)d_in[9];

    float* out   = (float*)d_out;
    float* gout  = out;          // first output: g_attn (scores scratch first)
    float* naout = out + BSS;    // second output: neibor_attn (attn in-place)

    // workspace layout (~39 MB)
    char* ws = (char*)d_ws;
    short*  xb   = (short*)(ws);                        // 16 MB  x (bf16)
    short*  wqt  = (short*)(ws + (16ull << 20));        //  2 MB  Wq^T (bf16)
    short*  wkt  = (short*)(ws + (18ull << 20));        //  2 MB  Wk^T (bf16)
    short*  m2t  = (short*)(ws + (20ull << 20));        //  2 MB  (Wq^T Wk)^T
    short*  tb   = (short*)(ws + (22ull << 20));        // 16 MB  t = x@M2
    double* cumd = (double*)(ws + (38ull << 20));       // 64 KB
    float*  uvec = (float*)(ws + (38ull << 20) + (1ull << 16)); // 4 KB
    float*  vvec = uvec + 1024;                         // 4 KB
    float*  c0   = vvec + 1024;                         // 4 B (padded to 256B)
    float*  pvec = c0 + 64;                             // 32 KB (8192 f32)
    float*  rvec = pvec + 8192;                         // 32 KB
    float*  pu   = rvec + 8192;                         // 64 KB (16x1024)
    float*  pv   = pu + 16384;                          // 64 KB

    bias_gemv1<<<dim3(8, 16), 256, 0, stream>>>(Wq, Wk, bk, bq, pu, pv);
    bias_gemv2<<<4, 256, 0, stream>>>(pu, pv, bk, bq, uvec, vvec, c0);
    ln_kernel<<<8192, 256, 0, stream>>>(context, gamma, beta, uvec, vvec,
                                        xb, pvec, rvec);
    cvt_t_kernel<<<dim3(32, 32, 2), 256, 0, stream>>>(Wq, Wk, wqt, wkt);
    // M2T[j][i] = sum_d Wkt[j][d] * Wqt[i][d]  ( = (Wq^T Wk)[i][j] )
    gemm_bf16<<<dim3(8, 8), 256, 0, stream>>>(wkt, wqt, nullptr, m2t);
    // t[q][j] = sum_i xb[q][i] * M2T[j][i]
    gemm_bf16<<<dim3(64, 8), 256, 0, stream>>>(xb, m2t, nullptr, tb);
    // scores[b][q][k] = (t[q].x[k] + p[q] + r[k] + c0) / 512
    gemm_scores<<<dim3(8, 8, 8), 256, 0, stream>>>(tb, xb, pvec, rvec, c0, gout);
    softmax_kernel<<<8192, 256, 0, stream>>>(gout, adj, naout);
    cum2_kernel<<<8, 1024, 0, stream>>>(naout, prior, cumd);
    na_g_kernel<<<dim3(1024, 8), 256, 0, stream>>>(naout, prior, cumd, gout);
}